// Round 8
// baseline (518.493 us; speedup 1.0000x reference)
//
#include <hip/hip_runtime.h>
#include <hip/hip_bf16.h>
#include <stdint.h>

#define IN_F   16080
#define NTREES 64
#define NLEAF  128
#define NCLS   16
#define NBATCH 64
#define M_TOT  (NBATCH*NTREES)     // 4096
#define OUT_HALF (M_TOT*NLEAF)     // 524288

#define BM 64
#define BK 64                          // K-step
#define KSPLIT 16
#define NSTEPS ((IN_F + BK - 1)/BK)    // 252 (251 full + 16-elem tail)
#define NMBLK  (M_TOT / BM)            // 64
#define WB_K   16192                   // padded K for Wb: covers prefetch at
                                       // s=252 (max gk+8 = 252*64+64 = 16192)

typedef __attribute__((ext_vector_type(8))) short short8;   // 8 x bf16
typedef __attribute__((ext_vector_type(4))) float f32x4;

typedef const __attribute__((address_space(1))) uint32_t gu32_t;
typedef __attribute__((address_space(3))) uint32_t su32_t;

// 8 fp32 -> short8 bf16 frag via packed RNE converts
__device__ __forceinline__ short8 cvt8(float4 lo, float4 hi){
  union { short8 s8; __hip_bfloat162 h2[4]; } u;
  u.h2[0] = __float22bfloat162_rn(make_float2(lo.x, lo.y));
  u.h2[1] = __float22bfloat162_rn(make_float2(lo.z, lo.w));
  u.h2[2] = __float22bfloat162_rn(make_float2(hi.x, hi.y));
  u.h2[3] = __float22bfloat162_rn(make_float2(hi.z, hi.w));
  return u.s8;
}

// W fp32 [128,16080] -> bf16 [128, WB_K=16192] (RNE, K-padded with zeros so
// the gemm's B loads never need tail guards). One block per leaf row.
__global__ __launch_bounds__(256)
void wcvt_kernel(const float* __restrict__ W, short* __restrict__ Wb){
  const int r = blockIdx.x;                       // 0..127
  const float* src = W  + (size_t)r * IN_F;
  short*       dst = Wb + (size_t)r * WB_K;
  for (int i = threadIdx.x * 8; i < WB_K; i += 256 * 8){
    if (i + 8 <= IN_F){                           // IN_F%8==0: exact cover
      float4 a = *(const float4*)(src + i);
      float4 b = *(const float4*)(src + i + 4);
      *(short8*)(dst + i) = cvt8(a, b);
    } else {                                      // pure zero pad region
      short8 z = {0,0,0,0,0,0,0,0};
      *(short8*)(dst + i) = z;
    }
  }
}

// ---------------- Fast path: LDS-free, barrier-free reg GEMM ---------------
// C = X[4096,16080] * W[128,16080]^T, slab split-K (16 slabs, plain stores).
//
// R8 structural change: NO LDS, NO barriers, NO manual waitcnt. R5 counters
// (MfmaUtil 3.2%, VALUBusy 9.9%, HBM 13.6%, occ 29%, conflicts 0) showed the
// barrier-locked LDS structure convoys all 16 waves/CU into the same
// issue/wait phase — latency exposed, every pipe idle. Here each wave is
// fully independent: it owns 16 rows x all 128 leaves, loads its B
// fragments (bf16, MFMA-ready) straight from the L2/LLC-resident padded Wb
// (4 MB), software-pipelined one step ahead (A raw fp32 likewise). The
// compiler derives exact counted vmcnt waits from program order; waves
// self-stagger, so per-wave latency hides under 16-way/CU TLP.
//
// Issued B traffic = 4096 waves x 16 steps x 16KB ~= 1.07 GB from L2/LLC
// (~13 TB/s demand vs 34 TB/s) — traded for zero synchronization.
__global__ __launch_bounds__(256, 4)   // cap 128 VGPR: 4 waves/SIMD
void gemm_reg_kernel(const float* __restrict__ X,
                     const short* __restrict__ Wb,
                     float* __restrict__ slabs){
  const int tid = threadIdx.x;
  const int m0  = blockIdx.x * BM;
  const int kc  = blockIdx.y;
  const int s0  = (kc * NSTEPS) / KSPLIT;
  const int s1  = ((kc + 1) * NSTEPS) / KSPLIT;

  const int lane = tid & 63;
  const int wv   = tid >> 6;      // m-strip index, 0..3 (16 rows each)
  const int fr   = lane & 15;     // row/col within 16x16 tile
  const int fq   = lane >> 4;     // k-quad

  f32x4 acc[8];
  #pragma unroll
  for (int nt = 0; nt < 8; ++nt) acc[nt] = (f32x4){0.f,0.f,0.f,0.f};

  const float* arow = X  + (size_t)(m0 + wv*16 + fr) * IN_F;
  const short* brow = Wb + (size_t)fr * WB_K + fq*8;   // + nt*16*WB_K + k0 + h*32

  float4 av[2][2];                // next-step A raw fp32 [h][q]
  short8 b0[8], b1[8];            // B frags for halves h=0 / h=1

  // A loads: value-guarded (zero past IN_F), address clamped in-bounds.
  #define LOAD_A(s_)                                                        \
    {                                                                       \
      const int kk = (s_) * BK;                                             \
      _Pragma("unroll")                                                     \
      for (int h = 0; h < 2; ++h)                                           \
        _Pragma("unroll")                                                   \
        for (int q = 0; q < 2; ++q){                                        \
          int gk = kk + h*32 + fq*8 + q*4;                                  \
          bool ok = (gk + 4 <= IN_F);                                       \
          float4 vv = *(const float4*)(arow + (ok ? gk : 0));               \
          av[h][q] = ok ? vv : make_float4(0.f,0.f,0.f,0.f);                \
        }                                                                   \
    }

  // B loads: Wb padded to WB_K, never OOB, no guards. 8 frags (nt) per half.
  #define LOAD_B(dst_, s_, h_)                                              \
    {                                                                       \
      const short* bp = brow + (s_) * BK + (h_) * 32;                       \
      _Pragma("unroll")                                                     \
      for (int nt = 0; nt < 8; ++nt)                                        \
        dst_[nt] = *(const short8*)(bp + (size_t)nt * (16 * WB_K));         \
    }

  // --- prologue: step s0 fully in flight ---
  LOAD_B(b0, s0, 0)
  LOAD_B(b1, s0, 1)
  LOAD_A(s0)

  for (int s = s0; s < s1; ++s){
    // consume A(s) (frees av), then prefetch A(s+1)
    short8 af0 = cvt8(av[0][0], av[0][1]);
    short8 af1 = cvt8(av[1][0], av[1][1]);
    LOAD_A(s + 1)

    // half h=0: consume b0, then reload b0 for s+1
    #pragma unroll
    for (int nt = 0; nt < 8; ++nt)
      acc[nt] = __builtin_amdgcn_mfma_f32_16x16x32_bf16(af0, b0[nt], acc[nt], 0, 0, 0);
    LOAD_B(b0, s + 1, 0)

    // half h=1: consume b1, then reload b1 for s+1
    #pragma unroll
    for (int nt = 0; nt < 8; ++nt)
      acc[nt] = __builtin_amdgcn_mfma_f32_16x16x32_bf16(af1, b1[nt], acc[nt], 0, 0, 0);
    LOAD_B(b1, s + 1, 1)
  }
  #undef LOAD_A
  #undef LOAD_B

  // --- slab store. C/D layout: col = lane&15, row = (lane>>4)*4 + reg ---
  const int rbase = m0 + wv*16 + fq*4;
  #pragma unroll
  for (int nt = 0; nt < 8; ++nt){
    int col = nt*16 + fr;
    #pragma unroll
    for (int r = 0; r < 4; ++r)
      slabs[(size_t)kc * OUT_HALF + (size_t)(rbase + r) * NLEAF + col]
          = acc[nt][r];
  }
}

// Epilogue for the slab path: reduce 16 partial slabs, then bias/hardtanh
// + 16-class softmax Gini.
__global__ __launch_bounds__(256)
void epilogue_slab_kernel(const float* __restrict__ slabs,
                          float* __restrict__ out,
                          const float* __restrict__ bias,
                          const float* __restrict__ contrib){
  int idx = blockIdx.x * 256 + threadIdx.x;   // < OUT_HALF
  int l   = idx & (NLEAF - 1);
  int row = idx >> 7;
  int t   = row & (NTREES - 1);

  float s = 0.f;
  #pragma unroll
  for (int kc = 0; kc < KSPLIT; ++kc)
    s += slabs[(size_t)kc * OUT_HALF + idx];
  s += bias[l];
  s = fminf(1.f, fmaxf(-1.f, s));
  out[idx] = s;

  const float4* cp = (const float4*)(contrib + (((size_t)t * NLEAF + l) << 4));
  float4 c0 = cp[0], c1 = cp[1], c2 = cp[2], c3 = cp[3];
  float v[16] = { s*c0.x, s*c0.y, s*c0.z, s*c0.w,
                  s*c1.x, s*c1.y, s*c1.z, s*c1.w,
                  s*c2.x, s*c2.y, s*c2.z, s*c2.w,
                  s*c3.x, s*c3.y, s*c3.z, s*c3.w };
  float m = v[0];
  #pragma unroll
  for (int c = 1; c < 16; ++c) m = fmaxf(m, v[c]);
  float se = 0.f, se2 = 0.f;
  #pragma unroll
  for (int c = 0; c < 16; ++c){
    float e = __expf(v[c] - m);
    se  += e;
    se2 += e * e;
  }
  out[OUT_HALF + idx] = (float)NCLS - se2 / (se * se);
}

// ---------------- Legacy path (harness-verified @429us) --------------------
// Used only when the workspace is too small. Needs 256 B of ws.
__global__ __launch_bounds__(256, 4)
void gemm_atomic_kernel(const float* __restrict__ X,
                        const float* __restrict__ Wg,
                        float* __restrict__ accbuf,
                        const float* __restrict__ zeropage){
  __shared__ __align__(16) float BsF[NLEAF * BK];   // 32 KB, fp32, chunk-swizzled

  const int tid = threadIdx.x;
  const int m0  = blockIdx.x * BM;
  const int kc  = blockIdx.y;
  const int s0  = (kc * NSTEPS) / KSPLIT;
  const int s1  = ((kc + 1) * NSTEPS) / KSPLIT;

  const int lane = tid & 63;
  const int wv   = tid >> 6;
  const int wm   = wv & 1;
  const int wn   = wv >> 1;
  const int fr   = lane & 15;
  const int fq   = lane >> 4;

  f32x4 acc[2][4];
  #pragma unroll
  for (int mt = 0; mt < 2; ++mt)
    #pragma unroll
    for (int nt = 0; nt < 4; ++nt) acc[mt][nt] = (f32x4){0.f,0.f,0.f,0.f};

  for (int s = s0; s < s1; ++s){
    const int k0 = s * BK;
    __syncthreads();

    float4 av[2][2][2];
    #pragma unroll
    for (int mt = 0; mt < 2; ++mt){
      const float* rowp = X + (size_t)(m0 + wm*32 + mt*16 + fr) * IN_F;
      #pragma unroll
      for (int h = 0; h < 2; ++h)
        #pragma unroll
        for (int q = 0; q < 2; ++q){
          int gk = k0 + h*32 + fq*8 + q*4;
          av[mt][h][q] = (gk + 4 <= IN_F) ? *(const float4*)(rowp + gk)
                                          : make_float4(0.f,0.f,0.f,0.f);
        }
    }

    #pragma unroll
    for (int j = 0; j < 8; ++j){
      int lin = j*256 + tid;
      int r   = lin >> 4;
      int p   = lin & 15;
      int c   = p ^ (r & 7);
      int gk  = k0 + c*4;
      const float* gp = (gk + 4 <= IN_F) ? (Wg + (size_t)r * IN_F + gk)
                                         : zeropage;
      __builtin_amdgcn_global_load_lds((gu32_t*)gp, (su32_t*)(BsF + lin*4),
                                       16, 0, 0);
    }

    short8 af[2][2];
    #pragma unroll
    for (int mt = 0; mt < 2; ++mt)
      #pragma unroll
      for (int h = 0; h < 2; ++h)
        af[mt][h] = cvt8(av[mt][h][0], av[mt][h][1]);

    __syncthreads();

    #pragma unroll
    for (int nt = 0; nt < 4; ++nt){
      const int l  = wn*64 + nt*16 + fr;
      const int xw = l & 7;
      const float* rowb = BsF + l*64;
      #pragma unroll
      for (int h = 0; h < 2; ++h){
        int c0 = h*8 + fq*2;
        float4 b0 = *(const float4*)(rowb + ((c0    ) ^ xw)*4);
        float4 b1 = *(const float4*)(rowb + ((c0 + 1) ^ xw)*4);
        short8 bf = cvt8(b0, b1);
        #pragma unroll
        for (int mt = 0; mt < 2; ++mt)
          acc[mt][nt] = __builtin_amdgcn_mfma_f32_16x16x32_bf16(
                            af[mt][h], bf, acc[mt][nt], 0, 0, 0);
      }
    }
  }

  #pragma unroll
  for (int mt = 0; mt < 2; ++mt){
    const int rbase = m0 + wm*32 + mt*16 + fq*4;
    #pragma unroll
    for (int nt = 0; nt < 4; ++nt){
      int col = wn*64 + nt*16 + fr;
      #pragma unroll
      for (int r = 0; r < 4; ++r)
        atomicAdd(&accbuf[(size_t)(rbase + r) * NLEAF + col], acc[mt][nt][r]);
    }
  }
}

__global__ __launch_bounds__(256)
void epilogue_inplace_kernel(float* __restrict__ out,
                             const float* __restrict__ bias,
                             const float* __restrict__ contrib){
  int idx = blockIdx.x * 256 + threadIdx.x;   // < OUT_HALF
  int l   = idx & (NLEAF - 1);
  int row = idx >> 7;
  int t   = row & (NTREES - 1);

  float s = out[idx] + bias[l];
  s = fminf(1.f, fmaxf(-1.f, s));
  out[idx] = s;

  const float4* cp = (const float4*)(contrib + (((size_t)t * NLEAF + l) << 4));
  float4 c0 = cp[0], c1 = cp[1], c2 = cp[2], c3 = cp[3];
  float v[16] = { s*c0.x, s*c0.y, s*c0.z, s*c0.w,
                  s*c1.x, s*c1.y, s*c1.z, s*c1.w,
                  s*c2.x, s*c2.y, s*c2.z, s*c2.w,
                  s*c3.x, s*c3.y, s*c3.z, s*c3.w };
  float m = v[0];
  #pragma unroll
  for (int c = 1; c < 16; ++c) m = fmaxf(m, v[c]);
  float se = 0.f, se2 = 0.f;
  #pragma unroll
  for (int c = 0; c < 16; ++c){
    float e = __expf(v[c] - m);
    se  += e;
    se2 += e * e;
  }
  out[OUT_HALF + idx] = (float)NCLS - se2 / (se * se);
}

extern "C" void kernel_launch(void* const* d_in, const int* in_sizes, int n_in,
                              void* d_out, int out_size, void* d_ws, size_t ws_size,
                              hipStream_t stream){
  const float* X       = (const float*)d_in[0];   // [64,64,16080]
  const float* Wg      = (const float*)d_in[1];   // [128,16080]
  const float* bias    = (const float*)d_in[2];   // [128]
  const float* contrib = (const float*)d_in[3];   // [64,128,16]
  float* out = (float*)d_out;

  const size_t SLAB_BYTES = (size_t)KSPLIT * OUT_HALF * sizeof(float); // 33.55 MB
  const size_t WB_BYTES   = (size_t)NLEAF * WB_K * sizeof(short);      // 4.15 MB
  char* ws = (char*)d_ws;

  dim3 g1(NMBLK, KSPLIT);

  if (ws_size >= SLAB_BYTES + WB_BYTES){
    // ws layout: [16 slabs 33.55MB][W_bf16 padded 4.15MB]
    float* slabs = (float*)ws;
    short* Wb    = (short*)(ws + SLAB_BYTES);
    wcvt_kernel<<<NLEAF, 256, 0, stream>>>(Wg, Wb);
    gemm_reg_kernel<<<g1, 256, 0, stream>>>(X, Wb, slabs);
    epilogue_slab_kernel<<<OUT_HALF / 256, 256, 0, stream>>>(slabs, out, bias, contrib);
  } else {
    // legacy harness-verified path: fp32 W staged per-step, atomic split-K.
    hipMemsetAsync(out, 0, (size_t)OUT_HALF * sizeof(float), stream);
    hipMemsetAsync(ws, 0, 256, stream);
    gemm_atomic_kernel<<<g1, 256, 0, stream>>>(X, Wg, out, (const float*)ws);
    epilogue_inplace_kernel<<<OUT_HALF / 256, 256, 0, stream>>>(out, bias, contrib);
  }
}